// Round 6
// baseline (268.393 us; speedup 1.0000x reference)
//
#include <hip/hip_runtime.h>
#include <math.h>

#define NB 4
#define NT 256
#define NS 1024
#define NH 256
#define BT 8            // t rows per BLOCK (4 waves x TT)
#define TT 2            // t rows per WAVE
#define SBK 128         // s per block slab
#define NSQ (NS / SBK)  // 8
#define BS (NB * NS)    // 4096 encoder rows

static constexpr float CTWO   = 2.8853900817779268f; // 2*log2(e)
static constexpr float LOG2E  = 1.4426950408889634f;
static constexpr float ACLAMP = 62.0f;

// ---------- merged projection (unchanged) ----------
__global__ __launch_bounds__(256) void proj_kernel(const float* __restrict__ Q,
                                                   const float* __restrict__ E,
                                                   const float* __restrict__ W_h,
                                                   const float* __restrict__ W_s,
                                                   float* __restrict__ tq,
                                                   float* __restrict__ te4) {
  __shared__ float As[32][68];
  __shared__ float Bs[32][68];
  const int tid = threadIdx.x;
  int r0 = blockIdx.x * 64;
  const int n0 = blockIdx.y * 64;
  const bool is_q = (r0 < NB * NT);
  const float* A;
  const float* W;
  if (is_q) { A = Q; W = W_h; }
  else      { A = E; W = W_s; r0 -= NB * NT; }
  const int tx = tid & 15;
  const int ty = tid >> 4;
  float acc[4][4] = {};
  for (int k0 = 0; k0 < NH; k0 += 32) {
    {
      const int r = tid >> 2;
      const int kq = (tid & 3) * 8;
      const float* src = A + (size_t)(r0 + r) * NH + k0 + kq;
      float4 v0 = *(const float4*)(src);
      float4 v1 = *(const float4*)(src + 4);
      As[kq + 0][r] = v0.x; As[kq + 1][r] = v0.y; As[kq + 2][r] = v0.z; As[kq + 3][r] = v0.w;
      As[kq + 4][r] = v1.x; As[kq + 5][r] = v1.y; As[kq + 6][r] = v1.z; As[kq + 7][r] = v1.w;
    }
    {
      const int k = tid >> 3;
      const int nq = (tid & 7) * 8;
      const float* src = W + (size_t)(k0 + k) * NH + n0 + nq;
      *(float4*)&Bs[k][nq]     = *(const float4*)(src);
      *(float4*)&Bs[k][nq + 4] = *(const float4*)(src + 4);
    }
    __syncthreads();
    #pragma unroll
    for (int k = 0; k < 32; ++k) {
      float4 a = *(const float4*)&As[k][ty * 4];
      float4 b = *(const float4*)&Bs[k][tx * 4];
      const float av[4] = {a.x, a.y, a.z, a.w};
      const float bv[4] = {b.x, b.y, b.z, b.w};
      #pragma unroll
      for (int i = 0; i < 4; ++i)
        #pragma unroll
        for (int j = 0; j < 4; ++j)
          acc[i][j] = fmaf(av[i], bv[j], acc[i][j]);
    }
    __syncthreads();
  }
  #pragma unroll
  for (int i = 0; i < 4; ++i) {
    float vals[4];
    #pragma unroll
    for (int j = 0; j < 4; ++j) {
      float x = acc[i][j] * CTWO;
      x = fminf(fmaxf(x, -ACLAMP), ACLAMP);
      vals[j] = __builtin_amdgcn_exp2f(x);
    }
    const int r = r0 + ty * 4 + i;
    if (is_q) {
      #pragma unroll
      for (int j = 0; j < 4; ++j)
        tq[(size_t)r * NH + n0 + tx * 4 + j] = vals[j];
    } else {
      const int h4 = (n0 >> 2) + tx;
      float4 w = {vals[0], vals[1], vals[2], vals[3]};
      *(float4*)&te4[((size_t)h4 * BS + r) * 4] = w;
    }
  }
}

// paired-rcp: v1/ta + v2/tb = (v1*tb + v2*ta) / (ta*tb)
#define PAIR(qa, ea, va, qb, eb, vb, ACC)                                  \
  {                                                                        \
    float ta = fmaf((qa), (ea), 1.0f);                                     \
    float tb = fmaf((qb), (eb), 1.0f);                                     \
    float num = fmaf((va), tb, (vb) * ta);                                 \
    float den = ta * tb;                                                   \
    ACC = fmaf(num, __builtin_amdgcn_rcpf(den), ACC);                      \
  }

// ---------- main: BLOCK owns (b, 8 t-rows, 128-s slab); te/enc staged via
// cached global loads -> registers -> ds_write (NOT global_load_lds: that
// path bypassed L2 reuse and went HBM-bound in R5). ----------
__global__ __launch_bounds__(256, 4) void attn_main_kernel(
    const float4* __restrict__ tqq,   // [row][64] float4 view of tq
    const float4* __restrict__ te4q,  // [h4][BS] float4 view
    const float4* __restrict__ enc4,  // [row][64] float4 view of enc
    const int* __restrict__ src_len,
    const float4* __restrict__ vq,    // [64]
    float4* __restrict__ po4, float* __restrict__ mbuf, float* __restrict__ lbuf) {
  __shared__ float4 buf[2048];          // 32 KB staging (te chunks, then enc chunks)
  __shared__ float p_lds[4][TT][SBK];   // 4 KB
  const int tid = threadIdx.x;
  const int wid = tid >> 6;
  const int lane = tid & 63;
  const int bx = blockIdx.x;
  const int x  = bx & 7;         // xcd (heuristic)
  const int j  = bx >> 3;
  const int k  = j & 3;
  const int tt8 = j >> 2;        // [0,32)
  const int b  = (x + k) & 3;
  const int sq = (x >> 2) + 2 * k;
  const int s0 = sq * SBK;
  const int len = src_len[b];
  const int btbase = b * NT + tt8 * BT;
  const int wrow = btbase + wid * TT;

  if (s0 >= len) {  // masked slab (uniform per block): combine skips po when m=-inf
    if (tid < BT) {
      mbuf[(size_t)(btbase + tid) * NSQ + sq] = -INFINITY;
      lbuf[(size_t)(btbase + tid) * NSQ + sq] = 0.f;
    }
    return;
  }

  // sum(v)
  float sumv;
  {
    float4 v4 = vq[lane];
    float sv = (v4.x + v4.y) + (v4.z + v4.w);
    #pragma unroll
    for (int o = 32; o > 0; o >>= 1) sv += __shfl_xor(sv, o, 64);
    sumv = sv;
  }

  const int gs0 = b * NS + s0;
  const bool va_ok = (s0 + lane) < len;
  const bool vb_ok = (s0 + 64 + lane) < len;

  float accA0[TT], accA1[TT], accB0[TT], accB1[TT];
  #pragma unroll
  for (int t = 0; t < TT; ++t) { accA0[t] = accA1[t] = accB0[t] = accB1[t] = 0.f; }

  // ---- score phase: 4 chunks of 64 h (16 h4-rows x 128 s = 32 KB) ----
  for (int c = 0; c < 4; ++c) {
    float4 stg[8];
    #pragma unroll
    for (int i = 0; i < 8; ++i) {
      const int f = tid + 256 * i;                 // [0,2048)
      stg[i] = te4q[(size_t)(c * 16 + (f >> 7)) * BS + gs0 + (f & 127)];  // coalesced, cached
    }
    __syncthreads();   // prev chunk consumed
    #pragma unroll
    for (int i = 0; i < 8; ++i) buf[tid + 256 * i] = stg[i];  // ds_write_b128
    __syncthreads();   // chunk ready
    #pragma unroll
    for (int h4c = 0; h4c < 16; ++h4c) {
      const int h4 = c * 16 + h4c;
      const float4 ea = buf[h4c * 128 + lane];
      const float4 eb = buf[h4c * 128 + 64 + lane];
      const float4 vv = vq[h4];                                    // scalar
      #pragma unroll
      for (int t = 0; t < TT; ++t) {
        const float4 q = tqq[(size_t)(wrow + t) * 64 + h4];        // scalar
        PAIR(q.x, ea.x, vv.x, q.y, ea.y, vv.y, accA0[t]);
        PAIR(q.z, ea.z, vv.z, q.w, ea.w, vv.w, accA1[t]);
        PAIR(q.x, eb.x, vv.x, q.y, eb.y, vv.y, accB0[t]);
        PAIR(q.z, eb.z, vv.z, q.w, eb.w, vv.w, accB1[t]);
      }
    }
  }

  // ---- wave-local softmax partials ----
  #pragma unroll
  for (int t = 0; t < TT; ++t) {
    float xa = va_ok ? fmaf(-2.f, accA0[t] + accA1[t], sumv) : -INFINITY;
    float xb = vb_ok ? fmaf(-2.f, accB0[t] + accB1[t], sumv) : -INFINITY;
    float m = fmaxf(xa, xb);
    #pragma unroll
    for (int o = 32; o > 0; o >>= 1) m = fmaxf(m, __shfl_xor(m, o, 64));
    float pa = __builtin_amdgcn_exp2f((xa - m) * LOG2E);
    float pb = __builtin_amdgcn_exp2f((xb - m) * LOG2E);
    float l = pa + pb;
    #pragma unroll
    for (int o = 32; o > 0; o >>= 1) l += __shfl_xor(l, o, 64);
    p_lds[wid][t][lane] = pa;
    p_lds[wid][t][64 + lane] = pb;
    if (lane == 0) {
      mbuf[(size_t)(wrow + t) * NSQ + sq] = m;
      lbuf[(size_t)(wrow + t) * NSQ + sq] = l;
    }
  }

  // ---- PV phase: 4 chunks of 32 s-rows (32 s x 64 f4 = 32 KB), reuse buf ----
  float4 o[TT];
  #pragma unroll
  for (int t = 0; t < TT; ++t) o[t] = make_float4(0.f, 0.f, 0.f, 0.f);
  for (int c = 0; c < 4; ++c) {
    float4 stg[8];
    #pragma unroll
    for (int i = 0; i < 8; ++i) {
      const int f = tid + 256 * i;                 // s = f>>6, col = f&63
      stg[i] = enc4[(size_t)(gs0 + c * 32 + (f >> 6)) * 64 + (f & 63)];   // coalesced, cached
    }
    __syncthreads();   // prev chunk consumed
    #pragma unroll
    for (int i = 0; i < 8; ++i) buf[tid + 256 * i] = stg[i];
    __syncthreads();   // chunk ready
    #pragma unroll 8
    for (int s = 0; s < 32; ++s) {
      const float4 e = buf[s * 64 + lane];
      #pragma unroll
      for (int t = 0; t < TT; ++t) {
        const float p = p_lds[wid][t][c * 32 + s];   // same-addr broadcast
        o[t].x = fmaf(p, e.x, o[t].x);
        o[t].y = fmaf(p, e.y, o[t].y);
        o[t].z = fmaf(p, e.z, o[t].z);
        o[t].w = fmaf(p, e.w, o[t].w);
      }
    }
  }
  #pragma unroll
  for (int t = 0; t < TT; ++t)
    po4[((size_t)(wrow + t) * NSQ + sq) * (NH / 4) + lane] = o[t];
}

// ---------- combine the NSQ slab-partials per (b,t); skip masked (m=-inf) ----------
__global__ __launch_bounds__(256) void combine_kernel(const float* __restrict__ po,
                                                      const float* __restrict__ mbuf,
                                                      const float* __restrict__ lbuf,
                                                      float* __restrict__ out) {
  const int bt = blockIdx.x;
  const int h = threadIdx.x;
  float m[NSQ], l[NSQ];
  float M = -INFINITY;
  #pragma unroll
  for (int i = 0; i < NSQ; ++i) {
    m[i] = mbuf[(size_t)bt * NSQ + i];
    l[i] = lbuf[(size_t)bt * NSQ + i];
    M = fmaxf(M, m[i]);
  }
  float L = 0.f, o = 0.f;
  #pragma unroll
  for (int i = 0; i < NSQ; ++i) {
    if (m[i] > -INFINITY) {  // uniform branch per block
      float w = __builtin_amdgcn_exp2f((m[i] - M) * LOG2E);
      L = fmaf(w, l[i], L);
      o = fmaf(w, po[((size_t)bt * NSQ + i) * NH + h], o);
    }
  }
  out[(size_t)bt * NH + h] = o / L;
}

extern "C" void kernel_launch(void* const* d_in, const int* in_sizes, int n_in,
                              void* d_out, int out_size, void* d_ws, size_t ws_size,
                              hipStream_t stream) {
  const float* query = (const float*)d_in[0];
  const float* enc   = (const float*)d_in[1];
  const int*   slen  = (const int*)d_in[2];
  const float* W_h   = (const float*)d_in[3];
  const float* W_s   = (const float*)d_in[4];
  const float* v     = (const float*)d_in[5];
  float* out = (float*)d_out;

  float* ws = (float*)d_ws;
  float* tq  = ws;                                 // NB*NT*NH          (1 MB)
  float* te4 = tq + (size_t)NB * NT * NH;          // NB*NS*NH          (4 MB)
  float* po  = te4 + (size_t)NB * NS * NH;         // NB*NT*NSQ*NH      (8 MB)
  float* mb  = po + (size_t)NB * NT * NSQ * NH;    // NB*NT*NSQ
  float* lb  = mb + (size_t)NB * NT * NSQ;         // NB*NT*NSQ

  hipLaunchKernelGGL(proj_kernel, dim3((NB * (NT + NS)) / 64, NH / 64), dim3(256), 0, stream,
                     query, enc, W_h, W_s, tq, te4);
  // blocks = NB * (NT/BT) * NSQ = 1024 (fully resident at 4 blocks/CU)
  hipLaunchKernelGGL(attn_main_kernel, dim3(NB * (NT / BT) * NSQ), dim3(256), 0, stream,
                     (const float4*)tq, (const float4*)te4, (const float4*)enc, slen,
                     (const float4*)v, (float4*)po, mb, lb);
  hipLaunchKernelGGL(combine_kernel, dim3(NB * NT), dim3(256), 0, stream, po, mb, lb, out);
}

// Round 7
// 101.777 us; speedup vs baseline: 2.6371x; 2.6371x over previous
//
#include <hip/hip_runtime.h>
#include <math.h>

#define NB 4
#define NT 256
#define NS 1024
#define NH 256
#define BT 4            // t rows per BLOCK (4 waves; 1 t-row each in softmax/PV)
#define SBK 128         // s per block slab
#define NSQ (NS / SBK)  // 8
#define BS (NB * NS)    // 4096 encoder rows

static constexpr float CTWO   = 2.8853900817779268f; // 2*log2(e)
static constexpr float LOG2E  = 1.4426950408889634f;
static constexpr float ACLAMP = 62.0f;

// ---------- merged projection (unchanged, proven) ----------
__global__ __launch_bounds__(256) void proj_kernel(const float* __restrict__ Q,
                                                   const float* __restrict__ E,
                                                   const float* __restrict__ W_h,
                                                   const float* __restrict__ W_s,
                                                   float* __restrict__ tq,
                                                   float* __restrict__ te4) {
  __shared__ float As[32][68];
  __shared__ float Bs[32][68];
  const int tid = threadIdx.x;
  int r0 = blockIdx.x * 64;
  const int n0 = blockIdx.y * 64;
  const bool is_q = (r0 < NB * NT);
  const float* A;
  const float* W;
  if (is_q) { A = Q; W = W_h; }
  else      { A = E; W = W_s; r0 -= NB * NT; }
  const int tx = tid & 15;
  const int ty = tid >> 4;
  float acc[4][4] = {};
  for (int k0 = 0; k0 < NH; k0 += 32) {
    {
      const int r = tid >> 2;
      const int kq = (tid & 3) * 8;
      const float* src = A + (size_t)(r0 + r) * NH + k0 + kq;
      float4 v0 = *(const float4*)(src);
      float4 v1 = *(const float4*)(src + 4);
      As[kq + 0][r] = v0.x; As[kq + 1][r] = v0.y; As[kq + 2][r] = v0.z; As[kq + 3][r] = v0.w;
      As[kq + 4][r] = v1.x; As[kq + 5][r] = v1.y; As[kq + 6][r] = v1.z; As[kq + 7][r] = v1.w;
    }
    {
      const int k = tid >> 3;
      const int nq = (tid & 7) * 8;
      const float* src = W + (size_t)(k0 + k) * NH + n0 + nq;
      *(float4*)&Bs[k][nq]     = *(const float4*)(src);
      *(float4*)&Bs[k][nq + 4] = *(const float4*)(src + 4);
    }
    __syncthreads();
    #pragma unroll
    for (int k = 0; k < 32; ++k) {
      float4 a = *(const float4*)&As[k][ty * 4];
      float4 b = *(const float4*)&Bs[k][tx * 4];
      const float av[4] = {a.x, a.y, a.z, a.w};
      const float bv[4] = {b.x, b.y, b.z, b.w};
      #pragma unroll
      for (int i = 0; i < 4; ++i)
        #pragma unroll
        for (int j = 0; j < 4; ++j)
          acc[i][j] = fmaf(av[i], bv[j], acc[i][j]);
    }
    __syncthreads();
  }
  #pragma unroll
  for (int i = 0; i < 4; ++i) {
    float vals[4];
    #pragma unroll
    for (int j = 0; j < 4; ++j) {
      float x = acc[i][j] * CTWO;
      x = fminf(fmaxf(x, -ACLAMP), ACLAMP);
      vals[j] = __builtin_amdgcn_exp2f(x);
    }
    const int r = r0 + ty * 4 + i;
    if (is_q) {
      #pragma unroll
      for (int j = 0; j < 4; ++j)
        tq[(size_t)r * NH + n0 + tx * 4 + j] = vals[j];
    } else {
      const int h4 = (n0 >> 2) + tx;
      float4 w = {vals[0], vals[1], vals[2], vals[3]};
      *(float4*)&te4[((size_t)h4 * BS + r) * 4] = w;
    }
  }
}

// paired-rcp: v1/ta + v2/tb = (v1*tb + v2*ta) / (ta*tb)
#define PAIR(qa, ea, va, qb, eb, vb, ACC)                                  \
  {                                                                        \
    float ta = fmaf((qa), (ea), 1.0f);                                     \
    float tb = fmaf((qb), (eb), 1.0f);                                     \
    float num = fmaf((va), tb, (vb) * ta);                                 \
    float den = ta * tb;                                                   \
    ACC = fmaf(num, __builtin_amdgcn_rcpf(den), ACC);                      \
  }

// ---------- main: block = (b, 4 t-rows, 128-s slab); 4 waves split the
// score work by h-half x t-pair (full 32-waves/CU occupancy). Data comes
// from plain cached loads (R4-proven path: FETCH ~4 MB; the R5/R6
// LDS-staging structure thrashed L2 -> 240 MB HBM fetch). ----------
__global__ __launch_bounds__(256) void attn_main_kernel(
    const float4* __restrict__ tqq,   // [row][64] float4 view of tq
    const float4* __restrict__ te4q,  // [h4][BS] float4 view
    const float4* __restrict__ enc4,  // [row][64] float4 view of enc
    const int* __restrict__ src_len,
    const float4* __restrict__ vq,    // [64]
    float4* __restrict__ po4, float* __restrict__ mbuf, float* __restrict__ lbuf) {
  __shared__ float part[2][BT][SBK];   // [h-half][t][s] partial score sums (4 KB)
  __shared__ float p_lds[BT][SBK];     // softmax probs (2 KB)
  const int tid = threadIdx.x;
  const int wid = tid >> 6;
  const int lane = tid & 63;
  const int bx = blockIdx.x;
  // low 5 bits -> (b, sq) bijective; per-XCD (round-robin bx%8) this fixes b
  // (tq/enc locality) and spans sq (mask-load balance).
  const int low5 = bx & 31;
  const int b  = low5 & 3;
  const int sq = ((low5 >> 2) + 2 * b) & 7;
  const int tg = bx >> 5;        // [0, 64) t-group
  const int btbase = b * NT + tg * BT;
  const int s0 = sq * SBK;
  const int len = src_len[b];

  if (s0 >= len) {  // masked slab (uniform per block): combine skips po when m=-inf
    if (tid < BT) {
      mbuf[(size_t)(btbase + tid) * NSQ + sq] = -INFINITY;
      lbuf[(size_t)(btbase + tid) * NSQ + sq] = 0.f;
    }
    return;
  }

  // sum(v): lane holds 4 components, wave shfl-reduce
  float sumv;
  {
    float4 v4 = vq[lane];
    float sv = (v4.x + v4.y) + (v4.z + v4.w);
    #pragma unroll
    for (int o = 32; o > 0; o >>= 1) sv += __shfl_xor(sv, o, 64);
    sumv = sv;
  }

  const int gs0 = b * NS + s0;

  // ---- score phase: wave = (t-pair, h-half) ----
  {
    const int tp = wid >> 1;         // t-pair 0..1 -> rows {2tp, 2tp+1}
    const int hh = wid & 1;          // h-half
    float accA[2] = {0.f, 0.f};      // s = s0 + lane
    float accB[2] = {0.f, 0.f};      // s = s0 + 64 + lane
    const int h4base = hh * 32;
    #pragma unroll 8
    for (int i = 0; i < 32; ++i) {
      const int h4 = h4base + i;
      const float4 ea = te4q[(size_t)h4 * BS + gs0 + lane];       // coalesced
      const float4 eb = te4q[(size_t)h4 * BS + gs0 + 64 + lane];
      const float4 vv = vq[h4];                                   // uniform
      #pragma unroll
      for (int t = 0; t < 2; ++t) {
        const float4 q = tqq[(size_t)(btbase + tp * 2 + t) * 64 + h4];  // uniform
        PAIR(q.x, ea.x, vv.x, q.y, ea.y, vv.y, accA[t]);
        PAIR(q.z, ea.z, vv.z, q.w, ea.w, vv.w, accA[t]);
        PAIR(q.x, eb.x, vv.x, q.y, eb.y, vv.y, accB[t]);
        PAIR(q.z, eb.z, vv.z, q.w, eb.w, vv.w, accB[t]);
      }
    }
    #pragma unroll
    for (int t = 0; t < 2; ++t) {
      part[hh][tp * 2 + t][lane]      = accA[t];
      part[hh][tp * 2 + t][64 + lane] = accB[t];
    }
  }
  __syncthreads();

  // ---- softmax: wave w owns t-row w ----
  const int r = wid;
  {
    const bool va_ok = (s0 + lane) < len;
    const bool vb_ok = (s0 + 64 + lane) < len;
    float sa = part[0][r][lane]      + part[1][r][lane];
    float sb = part[0][r][64 + lane] + part[1][r][64 + lane];
    float xa = va_ok ? fmaf(-2.f, sa, sumv) : -INFINITY;
    float xb = vb_ok ? fmaf(-2.f, sb, sumv) : -INFINITY;
    float m = fmaxf(xa, xb);
    #pragma unroll
    for (int o = 32; o > 0; o >>= 1) m = fmaxf(m, __shfl_xor(m, o, 64));
    float pa = __builtin_amdgcn_exp2f((xa - m) * LOG2E);
    float pb = __builtin_amdgcn_exp2f((xb - m) * LOG2E);
    float l = pa + pb;
    #pragma unroll
    for (int o = 32; o > 0; o >>= 1) l += __shfl_xor(l, o, 64);
    p_lds[r][lane] = pa;
    p_lds[r][64 + lane] = pb;
    if (lane == 0) {
      mbuf[(size_t)(btbase + r) * NSQ + sq] = m;
      lbuf[(size_t)(btbase + r) * NSQ + sq] = l;
    }
  }
  __syncthreads();

  // ---- PV: wave w owns t-row w; lane owns f4-column lane ----
  {
    float4 o = make_float4(0.f, 0.f, 0.f, 0.f);
    #pragma unroll 8
    for (int s = 0; s < SBK; ++s) {
      const float4 e = enc4[(size_t)(gs0 + s) * 64 + lane];  // coalesced
      const float pp = p_lds[r][s];                          // broadcast
      o.x = fmaf(pp, e.x, o.x);
      o.y = fmaf(pp, e.y, o.y);
      o.z = fmaf(pp, e.z, o.z);
      o.w = fmaf(pp, e.w, o.w);
    }
    po4[((size_t)(btbase + r) * NSQ + sq) * (NH / 4) + lane] = o;
  }
}

// ---------- combine the NSQ slab-partials per (b,t); skip masked (m=-inf) ----------
__global__ __launch_bounds__(256) void combine_kernel(const float* __restrict__ po,
                                                      const float* __restrict__ mbuf,
                                                      const float* __restrict__ lbuf,
                                                      float* __restrict__ out) {
  const int bt = blockIdx.x;
  const int h = threadIdx.x;
  float m[NSQ], l[NSQ];
  float M = -INFINITY;
  #pragma unroll
  for (int i = 0; i < NSQ; ++i) {
    m[i] = mbuf[(size_t)bt * NSQ + i];
    l[i] = lbuf[(size_t)bt * NSQ + i];
    M = fmaxf(M, m[i]);
  }
  float L = 0.f, o = 0.f;
  #pragma unroll
  for (int i = 0; i < NSQ; ++i) {
    if (m[i] > -INFINITY) {  // uniform branch per block
      float w = __builtin_amdgcn_exp2f((m[i] - M) * LOG2E);
      L = fmaf(w, l[i], L);
      o = fmaf(w, po[((size_t)bt * NSQ + i) * NH + h], o);
    }
  }
  out[(size_t)bt * NH + h] = o / L;
}

extern "C" void kernel_launch(void* const* d_in, const int* in_sizes, int n_in,
                              void* d_out, int out_size, void* d_ws, size_t ws_size,
                              hipStream_t stream) {
  const float* query = (const float*)d_in[0];
  const float* enc   = (const float*)d_in[1];
  const int*   slen  = (const int*)d_in[2];
  const float* W_h   = (const float*)d_in[3];
  const float* W_s   = (const float*)d_in[4];
  const float* v     = (const float*)d_in[5];
  float* out = (float*)d_out;

  float* ws = (float*)d_ws;
  float* tq  = ws;                                 // NB*NT*NH          (1 MB)
  float* te4 = tq + (size_t)NB * NT * NH;          // NB*NS*NH          (4 MB)
  float* po  = te4 + (size_t)NB * NS * NH;         // NB*NT*NSQ*NH      (8 MB)
  float* mb  = po + (size_t)NB * NT * NSQ * NH;    // NB*NT*NSQ
  float* lb  = mb + (size_t)NB * NT * NSQ;         // NB*NT*NSQ

  hipLaunchKernelGGL(proj_kernel, dim3((NB * (NT + NS)) / 64, NH / 64), dim3(256), 0, stream,
                     query, enc, W_h, W_s, tq, te4);
  // blocks = NB * NSQ * (NT/BT) = 2048 -> 8192 waves = full occupancy
  hipLaunchKernelGGL(attn_main_kernel, dim3(NB * NSQ * (NT / BT)), dim3(256), 0, stream,
                     (const float4*)tq, (const float4*)te4, (const float4*)enc, slen,
                     (const float4*)v, (float4*)po, mb, lb);
  hipLaunchKernelGGL(combine_kernel, dim3(NB * NT), dim3(256), 0, stream, po, mb, lb, out);
}

// Round 8
// 80.319 us; speedup vs baseline: 3.3416x; 1.2672x over previous
//
#include <hip/hip_runtime.h>
#include <math.h>

#define NB 4
#define NT 256
#define NS 1024
#define NH 256
#define SBK 64          // s window per wave (1 s per lane)
#define NSQ (NS / SBK)  // 16
#define WT 4            // t rows per wave (score AND pv) -> 4x te/enc reuse
#define BTR 16          // t rows per block (4 waves x WT)
#define BS (NB * NS)    // 4096 encoder rows

typedef _Float16 half4 __attribute__((ext_vector_type(4)));

static constexpr float CTWO   = 2.8853900817779268f; // 2*log2(e)
static constexpr float LOG2E  = 1.4426950408889634f;
static constexpr float ACLAMP = 62.0f;

// ---------- merged projection (unchanged, proven) ----------
__global__ __launch_bounds__(256) void proj_kernel(const float* __restrict__ Q,
                                                   const float* __restrict__ E,
                                                   const float* __restrict__ W_h,
                                                   const float* __restrict__ W_s,
                                                   float* __restrict__ tq,
                                                   float* __restrict__ te4) {
  __shared__ float As[32][68];
  __shared__ float Bs[32][68];
  const int tid = threadIdx.x;
  int r0 = blockIdx.x * 64;
  const int n0 = blockIdx.y * 64;
  const bool is_q = (r0 < NB * NT);
  const float* A;
  const float* W;
  if (is_q) { A = Q; W = W_h; }
  else      { A = E; W = W_s; r0 -= NB * NT; }
  const int tx = tid & 15;
  const int ty = tid >> 4;
  float acc[4][4] = {};
  for (int k0 = 0; k0 < NH; k0 += 32) {
    {
      const int r = tid >> 2;
      const int kq = (tid & 3) * 8;
      const float* src = A + (size_t)(r0 + r) * NH + k0 + kq;
      float4 v0 = *(const float4*)(src);
      float4 v1 = *(const float4*)(src + 4);
      As[kq + 0][r] = v0.x; As[kq + 1][r] = v0.y; As[kq + 2][r] = v0.z; As[kq + 3][r] = v0.w;
      As[kq + 4][r] = v1.x; As[kq + 5][r] = v1.y; As[kq + 6][r] = v1.z; As[kq + 7][r] = v1.w;
    }
    {
      const int k = tid >> 3;
      const int nq = (tid & 7) * 8;
      const float* src = W + (size_t)(k0 + k) * NH + n0 + nq;
      *(float4*)&Bs[k][nq]     = *(const float4*)(src);
      *(float4*)&Bs[k][nq + 4] = *(const float4*)(src + 4);
    }
    __syncthreads();
    #pragma unroll
    for (int k = 0; k < 32; ++k) {
      float4 a = *(const float4*)&As[k][ty * 4];
      float4 b = *(const float4*)&Bs[k][tx * 4];
      const float av[4] = {a.x, a.y, a.z, a.w};
      const float bv[4] = {b.x, b.y, b.z, b.w};
      #pragma unroll
      for (int i = 0; i < 4; ++i)
        #pragma unroll
        for (int j = 0; j < 4; ++j)
          acc[i][j] = fmaf(av[i], bv[j], acc[i][j]);
    }
    __syncthreads();
  }
  #pragma unroll
  for (int i = 0; i < 4; ++i) {
    float vals[4];
    #pragma unroll
    for (int j = 0; j < 4; ++j) {
      float x = acc[i][j] * CTWO;
      x = fminf(fmaxf(x, -ACLAMP), ACLAMP);
      vals[j] = __builtin_amdgcn_exp2f(x);
    }
    const int r = r0 + ty * 4 + i;
    if (is_q) {
      #pragma unroll
      for (int j = 0; j < 4; ++j)
        tq[(size_t)r * NH + n0 + tx * 4 + j] = vals[j];
    } else {
      const int h4 = (n0 >> 2) + tx;
      float4 w = {vals[0], vals[1], vals[2], vals[3]};
      *(float4*)&te4[((size_t)h4 * BS + r) * 4] = w;
    }
  }
}

// paired-rcp: v1/ta + v2/tb = (v1*tb + v2*ta) / (ta*tb)
#define PAIR(qa, ea, va, qb, eb, vb, ACC)                                  \
  {                                                                        \
    float ta = fmaf((qa), (ea), 1.0f);                                     \
    float tb = fmaf((qb), (eb), 1.0f);                                     \
    float num = fmaf((va), tb, (vb) * ta);                                 \
    float den = ta * tb;                                                   \
    ACC = fmaf(num, __builtin_amdgcn_rcpf(den), ACC);                      \
  }

// ---------- main: wave = (b, 4 t-rows, 64-s window), fully independent,
// zero barriers. Cached per-wave loads (R4-proven: FETCH ~4 MB). WT=4 cuts
// the dominant L2 traffic 2x vs R4 / 3x vs R7 (te 256 MB + enc 256 MB). ----------
__global__ __launch_bounds__(256) void attn_main_kernel(
    const float4* __restrict__ tqq,   // [row][64] float4 view of tq
    const float4* __restrict__ te4q,  // [h4][BS] float4 view
    const float4* __restrict__ enc4,  // [row][64] float4 view of enc
    const int* __restrict__ src_len,
    const float4* __restrict__ vq,    // [64]
    half4* __restrict__ poh, float* __restrict__ mbuf, float* __restrict__ lbuf) {
  __shared__ float4 p_lds[4 * SBK];   // [wave][s] -> probs of the wave's 4 t (4 KB)
  const int tid = threadIdx.x;
  const int wid = tid >> 6;
  const int lane = tid & 63;
  const int bx = blockIdx.x;
  // low6 -> (b, sq) bijective; per-XCD (round-robin bx%8) b is fixed
  // (te/enc locality) and sq spans 8 of 16 (mask-load balance).
  const int low6 = bx & 63;
  const int b  = low6 & 3;
  const int sq = ((low6 >> 2) + 4 * b) & 15;
  const int tg = bx >> 6;        // [0,16) t-group
  const int btbase = b * NT + tg * BTR;
  const int s0 = sq * SBK;
  const int len = src_len[b];

  if (s0 >= len) {  // masked window (uniform per block); combine skips po
    if (tid < BTR) {
      mbuf[(size_t)(btbase + tid) * NSQ + sq] = -INFINITY;
      lbuf[(size_t)(btbase + tid) * NSQ + sq] = 0.f;
    }
    return;
  }

  // sum(v): lane holds 4 components, wave shfl-reduce
  float sumv;
  {
    float4 v4 = vq[lane];
    float sv = (v4.x + v4.y) + (v4.z + v4.w);
    #pragma unroll
    for (int o = 32; o > 0; o >>= 1) sv += __shfl_xor(sv, o, 64);
    sumv = sv;
  }

  const int wrow = btbase + wid * WT;
  const int gs0 = b * NS + s0;
  const bool ok = (s0 + lane) < len;

  // ---- score: 64 h4 iters, 1 coalesced te load amortized over 4 t-rows ----
  float acc[WT] = {0.f, 0.f, 0.f, 0.f};
  const float4* tep = te4q + gs0 + lane;
  const float4* qp  = tqq + (size_t)wrow * 64;
  #pragma unroll 4
  for (int h4 = 0; h4 < 64; ++h4) {
    const float4 e  = tep[(size_t)h4 * BS];   // coalesced 1KB/wave (L2)
    const float4 vv = vq[h4];                 // L1-resident
    #pragma unroll
    for (int t = 0; t < WT; ++t) {
      const float4 q = qp[t * 64 + h4];       // wave-uniform addr, L1-resident
      PAIR(q.x, e.x, vv.x, q.y, e.y, vv.y, acc[t]);
      PAIR(q.z, e.z, vv.z, q.w, e.w, vv.w, acc[t]);
    }
  }

  // ---- wave-local softmax over the 64-s window (lane owns 1 s) ----
  float pv[WT];
  #pragma unroll
  for (int t = 0; t < WT; ++t) {
    float x = ok ? fmaf(-2.f, acc[t], sumv) : -INFINITY;
    float m = x;
    #pragma unroll
    for (int o = 32; o > 0; o >>= 1) m = fmaxf(m, __shfl_xor(m, o, 64));
    float p = __builtin_amdgcn_exp2f((x - m) * LOG2E);  // -inf -> 0
    float l = p;
    #pragma unroll
    for (int o = 32; o > 0; o >>= 1) l += __shfl_xor(l, o, 64);
    pv[t] = p;
    if (lane == 0) {
      mbuf[(size_t)(wrow + t) * NSQ + sq] = m;
      lbuf[(size_t)(wrow + t) * NSQ + sq] = l;
    }
  }
  // transpose p to [s][t] via same-wave LDS (compiler inserts lgkmcnt; no barrier)
  p_lds[wid * SBK + lane] = make_float4(pv[0], pv[1], pv[2], pv[3]);

  // ---- PV: 64 s iters, 1 coalesced enc load amortized over 4 t-rows ----
  float4 o[WT];
  #pragma unroll
  for (int t = 0; t < WT; ++t) o[t] = make_float4(0.f, 0.f, 0.f, 0.f);
  const float4* ep = enc4 + (size_t)gs0 * 64 + lane;
  #pragma unroll 4
  for (int s = 0; s < SBK; ++s) {
    const float4 e = ep[(size_t)s * 64];      // coalesced 1KB/wave (L2)
    const float4 p = p_lds[wid * SBK + s];    // same-addr broadcast
    o[0].x = fmaf(p.x, e.x, o[0].x); o[0].y = fmaf(p.x, e.y, o[0].y);
    o[0].z = fmaf(p.x, e.z, o[0].z); o[0].w = fmaf(p.x, e.w, o[0].w);
    o[1].x = fmaf(p.y, e.x, o[1].x); o[1].y = fmaf(p.y, e.y, o[1].y);
    o[1].z = fmaf(p.y, e.z, o[1].z); o[1].w = fmaf(p.y, e.w, o[1].w);
    o[2].x = fmaf(p.z, e.x, o[2].x); o[2].y = fmaf(p.z, e.y, o[2].y);
    o[2].z = fmaf(p.z, e.z, o[2].z); o[2].w = fmaf(p.z, e.w, o[2].w);
    o[3].x = fmaf(p.w, e.x, o[3].x); o[3].y = fmaf(p.w, e.y, o[3].y);
    o[3].z = fmaf(p.w, e.z, o[3].z); o[3].w = fmaf(p.w, e.w, o[3].w);
  }
  #pragma unroll
  for (int t = 0; t < WT; ++t) {
    half4 h;
    h.x = (_Float16)o[t].x; h.y = (_Float16)o[t].y;
    h.z = (_Float16)o[t].z; h.w = (_Float16)o[t].w;
    poh[((size_t)(wrow + t) * NSQ + sq) * 64 + lane] = h;
  }
}

// ---------- combine the NSQ=16 window-partials per (b,t); wave per bt ----------
__global__ __launch_bounds__(256) void combine_kernel(const half4* __restrict__ poh,
                                                      const float* __restrict__ mbuf,
                                                      const float* __restrict__ lbuf,
                                                      float4* __restrict__ out4) {
  const int bt = blockIdx.x * 4 + (threadIdx.x >> 6);
  const int lane = threadIdx.x & 63;
  float m[NSQ], l[NSQ];
  float M = -INFINITY;
  #pragma unroll
  for (int i = 0; i < NSQ; ++i) {
    m[i] = mbuf[(size_t)bt * NSQ + i];
    l[i] = lbuf[(size_t)bt * NSQ + i];
    M = fmaxf(M, m[i]);
  }
  float L = 0.f;
  float4 o = make_float4(0.f, 0.f, 0.f, 0.f);
  #pragma unroll
  for (int i = 0; i < NSQ; ++i) {
    if (m[i] > -INFINITY) {  // uniform branch per wave
      float w = __builtin_amdgcn_exp2f((m[i] - M) * LOG2E);
      L = fmaf(w, l[i], L);
      half4 h = poh[((size_t)bt * NSQ + i) * 64 + lane];
      o.x = fmaf(w, (float)h.x, o.x);
      o.y = fmaf(w, (float)h.y, o.y);
      o.z = fmaf(w, (float)h.z, o.z);
      o.w = fmaf(w, (float)h.w, o.w);
    }
  }
  const float r = __builtin_amdgcn_rcpf(L);
  o.x *= r; o.y *= r; o.z *= r; o.w *= r;
  out4[(size_t)bt * 64 + lane] = o;
}

extern "C" void kernel_launch(void* const* d_in, const int* in_sizes, int n_in,
                              void* d_out, int out_size, void* d_ws, size_t ws_size,
                              hipStream_t stream) {
  const float* query = (const float*)d_in[0];
  const float* enc   = (const float*)d_in[1];
  const int*   slen  = (const int*)d_in[2];
  const float* W_h   = (const float*)d_in[3];
  const float* W_s   = (const float*)d_in[4];
  const float* v     = (const float*)d_in[5];
  float* out = (float*)d_out;

  float* ws = (float*)d_ws;
  float* tq  = ws;                                 // NB*NT*NH floats   (1 MB)
  float* te4 = tq + (size_t)NB * NT * NH;          // NB*NS*NH floats   (4 MB)
  half4* poh = (half4*)(te4 + (size_t)NB * NS * NH);      // NB*NT*NSQ*NH halves (8.4 MB)
  float* mb  = (float*)((char*)poh + (size_t)NB * NT * NSQ * NH * 2);
  float* lb  = mb + (size_t)NB * NT * NSQ;

  hipLaunchKernelGGL(proj_kernel, dim3((NB * (NT + NS)) / 64, NH / 64), dim3(256), 0, stream,
                     query, enc, W_h, W_s, tq, te4);
  // blocks = NB * NSQ * (NT/BTR) = 4*16*16 = 1024 -> 4096 waves
  hipLaunchKernelGGL(attn_main_kernel, dim3(NB * NSQ * (NT / BTR)), dim3(256), 0, stream,
                     (const float4*)tq, (const float4*)te4, (const float4*)enc, slen,
                     (const float4*)v, poh, mb, lb);
  hipLaunchKernelGGL(combine_kernel, dim3(NB * NT / 4), dim3(256), 0, stream,
                     poh, mb, lb, (float4*)out);
}